// Round 11
// baseline (6962.369 us; speedup 1.0000x reference)
//
#include <hip/hip_runtime.h>
#include <math.h>

#define B_  32
#define T_  512
#define H_  1024
#define G4_ 4096
#define NT  512

typedef __attribute__((ext_vector_type(8))) _Float16 f16x8;
typedef __attribute__((ext_vector_type(4))) float   f32x4;

__device__ __forceinline__ float hardsig(float z) {
    return fminf(fmaxf(0.2f * z + 0.5f, 0.0f), 1.0f);
}
__device__ __forceinline__ float fast_tanh(float x) {
    float ax = fabsf(x);
    float e  = __expf(-2.0f * ax);
    float t  = (1.0f - e) / (1.0f + e);
    return copysignf(t, x);
}
__device__ __forceinline__ unsigned ldA(const unsigned* p) {
    return __hip_atomic_load(p, __ATOMIC_RELAXED, __HIP_MEMORY_SCOPE_AGENT);
}
__device__ __forceinline__ void stA32(unsigned* p, unsigned v) {
    __hip_atomic_store(p, v, __ATOMIC_RELAXED, __HIP_MEMORY_SCOPE_AGENT);
}
__device__ __forceinline__ unsigned long long ldA64(const void* p) {
    return __hip_atomic_load((const unsigned long long*)p, __ATOMIC_RELAXED, __HIP_MEMORY_SCOPE_AGENT);
}
__device__ __forceinline__ void stA64(void* p, unsigned long long v) {
    __hip_atomic_store((unsigned long long*)p, v, __ATOMIC_RELAXED, __HIP_MEMORY_SCOPE_AGENT);
}
__device__ __forceinline__ float f16bits_to_f(unsigned short us) {
    _Float16 hf; __builtin_memcpy(&hf, &us, 2);
    return (float)hf;
}
__device__ __forceinline__ unsigned umin2(unsigned a, unsigned b) { return a < b ? a : b; }

// register-only MFMA bursts (DVFS activity forcing; no memory traffic)
#define BURN_INIT f16x8 qj; _Pragma("unroll") for (int qi = 0; qi < 8; ++qi) qj[qi] = (_Float16)0.125f; \
                  f32x4 qa = {0,0,0,0}, qb = {0,0,0,0}, qc = {0,0,0,0}, qd = {0,0,0,0};
#define BURN16    _Pragma("unroll") for (int qi = 0; qi < 4; ++qi) { \
                      qa = __builtin_amdgcn_mfma_f32_16x16x32_f16(qj, qj, qa, 0, 0, 0); \
                      qb = __builtin_amdgcn_mfma_f32_16x16x32_f16(qj, qj, qb, 0, 0, 0); \
                      qc = __builtin_amdgcn_mfma_f32_16x16x32_f16(qj, qj, qc, 0, 0, 0); \
                      qd = __builtin_amdgcn_mfma_f32_16x16x32_f16(qj, qj, qd, 0, 0, 0); }
#define BURN4     qa = __builtin_amdgcn_mfma_f32_16x16x32_f16(qj, qj, qa, 0, 0, 0); \
                  qb = __builtin_amdgcn_mfma_f32_16x16x32_f16(qj, qj, qb, 0, 0, 0); \
                  qa = __builtin_amdgcn_mfma_f32_16x16x32_f16(qj, qj, qa, 0, 0, 0); \
                  qb = __builtin_amdgcn_mfma_f32_16x16x32_f16(qj, qj, qb, 0, 0, 0);
#define BURN_SINK asm volatile("" :: "v"(qa[0]), "v"(qb[0]), "v"(qc[0]), "v"(qd[0]));

// flag layout (dwords, PACKED for lane-parallel polling):
//  flag0 = ctr[0..127]   : dom0 block db (0..63), wave w (0..1) -> ctr[db*2+w] = t+1
//  flag1 = ctr[128..383] : dom1 block db (0..127), wave w -> ctr[128+db*2+w] = t+1
//  flagE = ctr[384..447] : engine block e (0..63) -> chunks completed

__global__ __launch_bounds__(NT, 1)
void lstm11(const float* __restrict__ x,
            const float* __restrict__ W0, const float* __restrict__ U0, const float* __restrict__ b0,
            const float* __restrict__ W1, const float* __restrict__ U1, const float* __restrict__ b1,
            _Float16* __restrict__ h1,       // [T][B][H] fp16
            _Float16* __restrict__ h2,       // [T][B][H] fp16
            _Float16* __restrict__ xzr,      // [4][8][B][4H] fp16 ring (bias-folded)
            const _Float16* __restrict__ zp, // [B][H] fp16 zeros
            unsigned* __restrict__ ctr,
            float* __restrict__ out)         // [B][H] fp32
{
    __shared__ __align__(16) char smem[148992];
    _Float16* Wl  = (_Float16*)smem;            // 128 KiB fragment-ordered weights
    float*    red = (float*)(smem + 131072);    // 17408 B [par][slot8][16][17]
    #define RED(par, slot, row, col) red[(((par) * 8 + (slot)) * 16 + (row)) * 17 + (col)]

    const int tid = threadIdx.x, bid = blockIdx.x;
    const int w = tid >> 6, l = tid & 63;
    const int koff = (l >> 4) * 8;

    // ============================ xz ENGINE (bid 192..255) ============================
    if (bid >= 192) {
        const int e = bid - 192, gbase = e * 64;
        for (int fi = tid; fi < 16384; fi += NT) {
            const int k = fi >> 4, rem = fi & 15;
            const float* src = W0 + (size_t)k * G4_ + gbase + rem * 4;
            float4 v = *(const float4*)src;
            const int kiG = k >> 5, jsub = 16 * ((k & 31) >> 3), e8 = k & 7;
            #pragma unroll
            for (int c = 0; c < 4; ++c) {
                const int j = rem * 4 + c, nf = j >> 4, lane = (j & 15) + jsub;
                float fv = (c == 0) ? v.x : (c == 1) ? v.y : (c == 2) ? v.z : v.w;
                Wl[((nf * 32 + kiG) * 64 + lane) * 8 + e8] = (_Float16)fv;
            }
        }
        float bb0[4];
        #pragma unroll
        for (int nf = 0; nf < 4; ++nf) bb0[nf] = b0[gbase + nf * 16 + (l & 15)];
        __syncthreads();

        for (int c = 0; c < 64; ++c) {
            if (c >= 4) {   // slot reuse guard: dom0 consumed chunk c-4. All waves burn-wait.
                const unsigned need = (unsigned)(8 * c - 24);
                BURN_INIT
                while (true) {
                    unsigned v = umin2(ldA(&ctr[l]), ldA(&ctr[64 + l]));
                    if (__all((int)(v >= need))) break;
                    BURN16
                }
                BURN_SINK
                __syncthreads();
            }

            f32x4 acc[2][4];
            #pragma unroll
            for (int p = 0; p < 2; ++p)
                #pragma unroll
                for (int nf = 0; nf < 4; ++nf) acc[p][nf] = (f32x4){0.f, 0.f, 0.f, 0.f};
            const float* xrow[2];
            #pragma unroll
            for (int p = 0; p < 2; ++p) {
                const int m = (w * 2 + p) * 16 + (l & 15);
                xrow[p] = x + ((size_t)(m & 31) * T_ + (8 * c + (m >> 5))) * 1024;
            }
            #pragma unroll 4
            for (int kiG = 0; kiG < 32; ++kiG) {
                const int kk = kiG * 32 + koff;
                f16x8 af[2];
                #pragma unroll
                for (int p = 0; p < 2; ++p) {
                    float4 v0 = *(const float4*)&xrow[p][kk];
                    float4 v1 = *(const float4*)&xrow[p][kk + 4];
                    af[p][0]=(_Float16)v0.x; af[p][1]=(_Float16)v0.y;
                    af[p][2]=(_Float16)v0.z; af[p][3]=(_Float16)v0.w;
                    af[p][4]=(_Float16)v1.x; af[p][5]=(_Float16)v1.y;
                    af[p][6]=(_Float16)v1.z; af[p][7]=(_Float16)v1.w;
                }
                #pragma unroll
                for (int nf = 0; nf < 4; ++nf) {
                    f16x8 bf = *(const f16x8*)&Wl[((nf * 32 + kiG) * 64 + l) * 8];
                    acc[0][nf] = __builtin_amdgcn_mfma_f32_16x16x32_f16(af[0], bf, acc[0][nf], 0, 0, 0);
                    acc[1][nf] = __builtin_amdgcn_mfma_f32_16x16x32_f16(af[1], bf, acc[1][nf], 0, 0, 0);
                }
            }
            #pragma unroll
            for (int p = 0; p < 2; ++p)
                #pragma unroll
                for (int nf = 0; nf < 4; ++nf)
                    #pragma unroll
                    for (int i = 0; i < 4; ++i) {
                        _Float16 hf = (_Float16)(acc[p][nf][i] + bb0[nf]);   // bias folded
                        unsigned short us; __builtin_memcpy(&us, &hf, 2);
                        unsigned up = us;
                        unsigned op = (unsigned)__shfl_xor((int)up, 1);
                        if (!(l & 1)) {
                            const int m = (w * 2 + p) * 16 + (l >> 4) * 4 + i;
                            size_t off = (((size_t)(c & 3) * 8 + (m >> 5)) * B_ + (m & 31)) * G4_
                                       + gbase + nf * 16 + ((l & 15) & ~1);
                            stA32((unsigned*)&xzr[off], up | (op << 16));
                        }
                    }
            asm volatile("s_waitcnt vmcnt(0)" ::: "memory");
            __syncthreads();
            if (tid == 0) stA32(&ctr[384 + e], (unsigned)(c + 1));
        }
        // done producing: burn until dom1 finishes (keeps clocks up; bounded by dom1 completion)
        {
            BURN_INIT
            while (true) {
                unsigned v = umin2(umin2(ldA(&ctr[128 + l]), ldA(&ctr[192 + l])),
                                   umin2(ldA(&ctr[256 + l]), ldA(&ctr[320 + l])));
                if (__all((int)(v >= (unsigned)T_))) break;
                BURN16
            }
            BURN_SINK
        }
        return;
    }

    // ============================ DOM0: layer-0, 64 blocks x 16 cols ============================
    if (bid < 64) {
        const int jb = bid * 16;
        for (int fi = tid; fi < 16384; fi += NT) {   // U0 -> frag LDS
            const int k = fi >> 4, rem = fi & 15, g = rem >> 2, jq = (rem & 3) * 4;
            const float* src = U0 + (size_t)k * G4_ + g * 1024 + jb + jq;
            float4 v = *(const float4*)src;
            const int kiG = k >> 5, jsub = 16 * ((k & 31) >> 3), e8 = k & 7;
            #pragma unroll
            for (int c = 0; c < 4; ++c) {
                const int lane = (jq + c) + jsub;
                float fv = (c == 0) ? v.x : (c == 1) ? v.y : (c == 2) ? v.z : v.w;
                Wl[((g * 32 + kiG) * 64 + lane) * 8 + e8] = (_Float16)fv;
            }
        }
        const int mt = w >> 2, g = w & 3;
        const int arow = mt * 16 + (l & 15);
        const int cidx = w * 64 + l;             // combine thread id (valid w<2)
        const int cb = cidx >> 2, j4 = (cidx & 3) * 4;
        float creg[4] = {0.f, 0.f, 0.f, 0.f};
        __syncthreads();

        for (int t = 0; t < T_; ++t) {
            const int par = t & 1;
            // lane-parallel flag poll with MFMA burn between checks
            {
                const bool need0 = (t > 0);
                const bool needE = (w < 2);
                const unsigned xt = (unsigned)((t >> 3) + 1);
                if (need0 || needE) {
                    BURN_INIT
                    while (true) {
                        bool ok = true;
                        if (need0) {
                            unsigned v0 = umin2(ldA(&ctr[l]), ldA(&ctr[64 + l]));
                            ok = (v0 >= (unsigned)t);
                        }
                        if (needE) {
                            unsigned ve = ldA(&ctr[384 + l]);
                            ok = ok && (ve >= xt);
                        }
                        if (__all((int)ok)) break;
                        BURN4
                    }
                    BURN_SINK
                }
            }
            asm volatile("" ::: "memory");

            // combine waves: issue xz loads early (overlap with MFMA)
            unsigned long long xzq[4];
            if (w < 2) {
                const size_t xbase = (((size_t)((t >> 3) & 3) * 8 + (t & 7)) * B_ + cb) * G4_ + jb + j4;
                #pragma unroll
                for (int gg = 0; gg < 4; ++gg) xzq[gg] = ldA64(&xzr[xbase + gg * 1024]);
            }

            // A-loads fully hoisted, 4 MFMA chains
            const _Float16* hp = t ? h1 + ((size_t)(t - 1) * B_ + arow) * H_
                                   : zp + (size_t)arow * H_;
            f16x8 a[32];
            #pragma unroll
            for (int k = 0; k < 32; ++k) a[k] = *(const f16x8*)&hp[k * 32 + koff];
            f32x4 ac0 = {0,0,0,0}, ac1 = {0,0,0,0}, ac2 = {0,0,0,0}, ac3 = {0,0,0,0};
            #pragma unroll
            for (int k = 0; k < 32; k += 4) {
                ac0 = __builtin_amdgcn_mfma_f32_16x16x32_f16(a[k+0], *(const f16x8*)&Wl[((g*32+k+0)*64+l)*8], ac0, 0, 0, 0);
                ac1 = __builtin_amdgcn_mfma_f32_16x16x32_f16(a[k+1], *(const f16x8*)&Wl[((g*32+k+1)*64+l)*8], ac1, 0, 0, 0);
                ac2 = __builtin_amdgcn_mfma_f32_16x16x32_f16(a[k+2], *(const f16x8*)&Wl[((g*32+k+2)*64+l)*8], ac2, 0, 0, 0);
                ac3 = __builtin_amdgcn_mfma_f32_16x16x32_f16(a[k+3], *(const f16x8*)&Wl[((g*32+k+3)*64+l)*8], ac3, 0, 0, 0);
            }
            f32x4 acc = (ac0 + ac1) + (ac2 + ac3);
            #pragma unroll
            for (int i = 0; i < 4; ++i)
                RED(par, mt * 4 + g, (l >> 4) * 4 + i, (l & 15)) = acc[i];
            __syncthreads();   // the only per-step barrier

            if (w < 2) {
                asm volatile("s_waitcnt vmcnt(0)" ::: "memory");   // xz loads done
                const int rmt = cb >> 4, row = cb & 15;
                unsigned long long pk = 0;
                float hv4[4];
                #pragma unroll
                for (int c = 0; c < 4; ++c) {
                    float z[4];
                    #pragma unroll
                    for (int gg = 0; gg < 4; ++gg) {
                        float xv = f16bits_to_f((unsigned short)((xzq[gg] >> (16 * c)) & 0xffffu));
                        z[gg] = RED(par, rmt * 4 + gg, row, j4 + c) + xv;
                    }
                    float ig = hardsig(z[0]), fg = hardsig(z[1]);
                    float gv = fast_tanh(z[2]), og = hardsig(z[3]);
                    creg[c] = fg * creg[c] + ig * gv;
                    hv4[c] = og * fast_tanh(creg[c]);
                    _Float16 hf = (_Float16)hv4[c];
                    unsigned short us; __builtin_memcpy(&us, &hf, 2);
                    pk |= ((unsigned long long)us) << (16 * c);
                }
                stA64(&h1[((size_t)t * B_ + cb) * H_ + jb + j4], pk);
                asm volatile("s_waitcnt vmcnt(0)" ::: "memory");   // publish ACKed at LLC
                if (l == 0) stA32(&ctr[bid * 2 + w], (unsigned)(t + 1));
            }
        }
        return;
    }

    // ============================ DOM1: layer-1, 128 blocks x 8 cols (bid 64..191) ============================
    {
        const int db = bid - 64, jb8 = db * 8;
        for (int m = 0; m < 2; ++m) {                 // W1,U1 -> frag LDS
            const float* M = m ? U1 : W1;
            for (int fi = tid; fi < 8192; fi += NT) {
                const int k = fi >> 3, rem = fi & 7, g = rem >> 1, jq = (rem & 1) * 4;
                const float* src = M + (size_t)k * G4_ + g * 1024 + jb8 + jq;
                float4 v = *(const float4*)src;
                const int kiG = k >> 5, jsub = 16 * ((k & 31) >> 3), e8 = k & 7;
                #pragma unroll
                for (int c = 0; c < 4; ++c) {
                    const int j = g * 8 + jq + c, nf = j >> 4, lane = (j & 15) + jsub;
                    float fv = (c == 0) ? v.x : (c == 1) ? v.y : (c == 2) ? v.z : v.w;
                    Wl[(((m * 2 + nf) * 32 + kiG) * 64 + lane) * 8 + e8] = (_Float16)fv;
                }
            }
        }
        const int role = w >> 2, mt = (w >> 1) & 1, nf = w & 1;
        const int arow = mt * 16 + (l & 15);
        const int cidx = w * 64 + l;             // combine thread id (valid w<2)
        const int cb = cidx >> 2, j2 = (cidx & 3) * 2;
        float creg[2] = {0.f, 0.f};
        float bias_[4][2];
        if (w < 2) {
            #pragma unroll
            for (int g = 0; g < 4; ++g)
                #pragma unroll
                for (int c = 0; c < 2; ++c)
                    bias_[g][c] = b1[(size_t)g * H_ + jb8 + j2 + c];
        }
        __syncthreads();

        for (int t = 0; t < T_; ++t) {
            const int par = t & 1;
            // lane-parallel flag poll per role, MFMA burn between checks
            if (role == 0) {
                const bool guard = (t >= 2);
                BURN_INIT
                while (true) {
                    unsigned v0 = umin2(ldA(&ctr[l]), ldA(&ctr[64 + l]));
                    bool ok = (v0 >= (unsigned)(t + 1));
                    if (guard) {
                        unsigned v1 = umin2(umin2(ldA(&ctr[128 + l]), ldA(&ctr[192 + l])),
                                            umin2(ldA(&ctr[256 + l]), ldA(&ctr[320 + l])));
                        ok = ok && (v1 >= (unsigned)(t - 1));
                    }
                    if (__all((int)ok)) break;
                    BURN4
                }
                BURN_SINK
            } else if (t > 0) {
                BURN_INIT
                while (true) {
                    unsigned v1 = umin2(umin2(ldA(&ctr[128 + l]), ldA(&ctr[192 + l])),
                                        umin2(ldA(&ctr[256 + l]), ldA(&ctr[320 + l])));
                    if (__all((int)(v1 >= (unsigned)t))) break;
                    BURN4
                }
                BURN_SINK
            }
            asm volatile("" ::: "memory");

            const _Float16* hp;
            if (role == 0) hp = h1 + ((size_t)t * B_ + arow) * H_;
            else           hp = t ? h2 + ((size_t)(t - 1) * B_ + arow) * H_
                                  : zp + (size_t)arow * H_;
            f16x8 a[32];
            #pragma unroll
            for (int k = 0; k < 32; ++k) a[k] = *(const f16x8*)&hp[k * 32 + koff];
            const int ws8 = (role * 2 + nf) * 32;
            f32x4 ac0 = {0,0,0,0}, ac1 = {0,0,0,0}, ac2 = {0,0,0,0}, ac3 = {0,0,0,0};
            #pragma unroll
            for (int k = 0; k < 32; k += 4) {
                ac0 = __builtin_amdgcn_mfma_f32_16x16x32_f16(a[k+0], *(const f16x8*)&Wl[((ws8+k+0)*64+l)*8], ac0, 0, 0, 0);
                ac1 = __builtin_amdgcn_mfma_f32_16x16x32_f16(a[k+1], *(const f16x8*)&Wl[((ws8+k+1)*64+l)*8], ac1, 0, 0, 0);
                ac2 = __builtin_amdgcn_mfma_f32_16x16x32_f16(a[k+2], *(const f16x8*)&Wl[((ws8+k+2)*64+l)*8], ac2, 0, 0, 0);
                ac3 = __builtin_amdgcn_mfma_f32_16x16x32_f16(a[k+3], *(const f16x8*)&Wl[((ws8+k+3)*64+l)*8], ac3, 0, 0, 0);
            }
            f32x4 acc = (ac0 + ac1) + (ac2 + ac3);
            #pragma unroll
            for (int i = 0; i < 4; ++i)
                RED(par, role * 4 + mt * 2 + nf, (l >> 4) * 4 + i, (l & 15)) = acc[i];
            __syncthreads();   // the only per-step barrier

            if (w < 2) {
                const int rmt = cb >> 4, row = cb & 15;
                unsigned pk = 0;
                float hv2[2];
                #pragma unroll
                for (int c = 0; c < 2; ++c) {
                    float z[4];
                    #pragma unroll
                    for (int g = 0; g < 4; ++g) {
                        const int j = g * 8 + j2 + c, nff = j >> 4, fc = j & 15;
                        z[g] = RED(par, 0 + rmt * 2 + nff, row, fc)
                             + RED(par, 4 + rmt * 2 + nff, row, fc) + bias_[g][c];
                    }
                    float ig = hardsig(z[0]), fg = hardsig(z[1]);
                    float gv = fast_tanh(z[2]), og = hardsig(z[3]);
                    creg[c] = fg * creg[c] + ig * gv;
                    hv2[c] = og * fast_tanh(creg[c]);
                    _Float16 hf = (_Float16)hv2[c];
                    unsigned short us; __builtin_memcpy(&us, &hf, 2);
                    pk |= ((unsigned)us) << (16 * c);
                }
                stA32((unsigned*)&h2[((size_t)t * B_ + cb) * H_ + jb8 + j2], pk);
                if (t == T_ - 1) *(float2*)&out[(size_t)cb * H_ + jb8 + j2] = make_float2(hv2[0], hv2[1]);
                asm volatile("s_waitcnt vmcnt(0)" ::: "memory");   // publish ACKed
                if (l == 0) stA32(&ctr[128 + db * 2 + w], (unsigned)(t + 1));
            }
        }
    }
}

extern "C" void kernel_launch(void* const* d_in, const int* in_sizes, int n_in,
                              void* d_out, int out_size, void* d_ws, size_t ws_size,
                              hipStream_t stream) {
    const float* x  = (const float*)d_in[0];
    const float* W0 = (const float*)d_in[1];
    const float* U0 = (const float*)d_in[2];
    const float* b0 = (const float*)d_in[3];
    const float* W1 = (const float*)d_in[4];
    const float* U1 = (const float*)d_in[5];
    const float* b1 = (const float*)d_in[6];
    float* out = (float*)d_out;

    char* ws = (char*)d_ws;
    const size_t off_h1 = 0;          // 32 MiB  h1 fp16 [T][B][H]
    const size_t off_h2 = 33554432;   // 32 MiB  h2 fp16 [T][B][H]
    const size_t off_xz = 67108864;   //  8 MiB  xz ring fp16 [4][8][B][4H]
    const size_t off_zp = 75497472;   // 64 KiB  fp16 zeros
    const size_t off_ct = 75563008;   //  8 KiB  flags

    _Float16* h1  = (_Float16*)(ws + off_h1);
    _Float16* h2  = (_Float16*)(ws + off_h2);
    _Float16* xzr = (_Float16*)(ws + off_xz);
    _Float16* zp  = (_Float16*)(ws + off_zp);
    unsigned* ctr = (unsigned*)(ws + off_ct);

    // reset zero page + flags every launch (graph-capture safe)
    hipMemsetAsync(ws + off_zp, 0, 65536 + 8192, stream);

    hipLaunchKernelGGL(lstm11, dim3(256), dim3(NT), 0, stream,
                       x, W0, U0, b0, W1, U1, b1,
                       h1, h2, xzr, zp, ctr, out);
}

// Round 12
// 4194.582 us; speedup vs baseline: 1.6598x; 1.6598x over previous
//
#include <hip/hip_runtime.h>
#include <math.h>

#define B_  32
#define T_  512
#define H_  1024
#define G4_ 4096
#define NT  512
#define ROWP 1032   // padded LDS row (f16): 2064 B -> 16B-aligned, 2-way banks max
#define WROW 264    // load_wfrags bounce row pad

typedef __attribute__((ext_vector_type(8))) _Float16 f16x8;
typedef __attribute__((ext_vector_type(4))) float   f32x4;

__device__ __forceinline__ float hardsig(float z) {
    return fminf(fmaxf(0.2f * z + 0.5f, 0.0f), 1.0f);
}
__device__ __forceinline__ float fast_tanh(float x) {
    float ax = fabsf(x);
    float e  = __expf(-2.0f * ax);
    float t  = (1.0f - e) / (1.0f + e);
    return copysignf(t, x);
}
__device__ __forceinline__ unsigned ldA(const unsigned* p) {
    return __hip_atomic_load(p, __ATOMIC_RELAXED, __HIP_MEMORY_SCOPE_AGENT);
}
__device__ __forceinline__ void stA32(unsigned* p, unsigned v) {
    __hip_atomic_store(p, v, __ATOMIC_RELAXED, __HIP_MEMORY_SCOPE_AGENT);
}
__device__ __forceinline__ unsigned long long ldA64(const void* p) {
    return __hip_atomic_load((const unsigned long long*)p, __ATOMIC_RELAXED, __HIP_MEMORY_SCOPE_AGENT);
}
__device__ __forceinline__ void stA64(void* p, unsigned long long v) {
    __hip_atomic_store((unsigned long long*)p, v, __ATOMIC_RELAXED, __HIP_MEMORY_SCOPE_AGENT);
}
__device__ __forceinline__ float f16bits_to_f(unsigned short us) {
    _Float16 hf; __builtin_memcpy(&hf, &us, 2);
    return (float)hf;
}
__device__ __forceinline__ unsigned umin2(unsigned a, unsigned b) { return a < b ? a : b; }

// Stage a [1024 k] x [64 gate-col] fp32 weight slice into per-wave MFMA B-fragments
// (registers/AGPRs), bouncing through LDS. Proven in r7.
__device__ __forceinline__ void load_wfrags(const float* M, int colbase, int myrow,
                                            int koff, bool keep, f16x8* wf, _Float16* st) {
    for (int kc = 0; kc < 4; ++kc) {
        __syncthreads();
        #pragma unroll
        for (int it = 0; it < 4; ++it) {
            int id  = it * NT + (int)threadIdx.x;   // 0..2047
            int kl  = id >> 3, gc8 = id & 7;
            int gcol = (gc8 >> 1) * 1024 + colbase + (gc8 & 1) * 8;
            const float* src = M + (size_t)(kc * 256 + kl) * G4_ + gcol;
            float4 v0 = *(const float4*)src;
            float4 v1 = *(const float4*)(src + 4);
            int rb = gc8 * 8;
            st[(rb+0)*WROW+kl]=(_Float16)v0.x; st[(rb+1)*WROW+kl]=(_Float16)v0.y;
            st[(rb+2)*WROW+kl]=(_Float16)v0.z; st[(rb+3)*WROW+kl]=(_Float16)v0.w;
            st[(rb+4)*WROW+kl]=(_Float16)v1.x; st[(rb+5)*WROW+kl]=(_Float16)v1.y;
            st[(rb+6)*WROW+kl]=(_Float16)v1.z; st[(rb+7)*WROW+kl]=(_Float16)v1.w;
        }
        __syncthreads();
        if (keep) {
            #pragma unroll
            for (int kj = 0; kj < 8; ++kj)
                wf[kc*8+kj] = *(const f16x8*)&st[myrow * WROW + kj * 32 + koff];
        }
    }
    __syncthreads();
}

// flag layout (dwords): dom0 @ ctr[0..127] (64 blk x 2 waves), dom1 @ ctr[128..255],
// engine @ ctr[384+e] (64). Flag value = steps (chunks) completed.

__global__ __launch_bounds__(NT, 1)
void lstm12(const float* __restrict__ x,
            const float* __restrict__ W0, const float* __restrict__ U0, const float* __restrict__ b0,
            const float* __restrict__ W1, const float* __restrict__ U1, const float* __restrict__ b1,
            _Float16* __restrict__ h1,       // [T][B][H] fp16
            _Float16* __restrict__ h2,       // [T][B][H] fp16
            _Float16* __restrict__ xzr,      // [4][8][B][4H] fp16 ring (b0 folded in)
            const _Float16* __restrict__ zp, // [B][H] fp16 zeros
            unsigned* __restrict__ ctr,
            float* __restrict__ out)         // [B][H] fp32
{
    __shared__ __align__(16) char smem[149504];

    const int tid = threadIdx.x, bid = blockIdx.x;
    const int w = tid >> 6, l = tid & 63;
    const int koff = (l >> 4) * 8;

    // ============================ xz ENGINE (bid 128..191) ============================
    if (bid >= 128) {
        _Float16* Wl = (_Float16*)smem;     // 128 KiB fragment-ordered W0 slice
        const int e = bid - 128, gbase = e * 64;
        for (int fi = tid; fi < 16384; fi += NT) {
            const int k = fi >> 4, rem = fi & 15;
            const float* src = W0 + (size_t)k * G4_ + gbase + rem * 4;
            float4 v = *(const float4*)src;
            const int kiG = k >> 5, jsub = 16 * ((k & 31) >> 3), e8 = k & 7;
            #pragma unroll
            for (int c = 0; c < 4; ++c) {
                const int j = rem * 4 + c, nf = j >> 4, lane = (j & 15) + jsub;
                float fv = (c == 0) ? v.x : (c == 1) ? v.y : (c == 2) ? v.z : v.w;
                Wl[((nf * 32 + kiG) * 64 + lane) * 8 + e8] = (_Float16)fv;
            }
        }
        float bb0[4];
        #pragma unroll
        for (int nf = 0; nf < 4; ++nf) bb0[nf] = b0[gbase + nf * 16 + (l & 15)];
        __syncthreads();

        for (int c = 0; c < 64; ++c) {
            if (c >= 4) {   // ring-slot reuse guard: dom0 consumed chunk c-4
                if (w == 0) {
                    const unsigned need = (unsigned)(8 * c - 24);
                    while (true) {
                        unsigned v = umin2(ldA(&ctr[2 * l]), ldA(&ctr[2 * l + 1]));
                        if (__all((int)(v >= need))) break;
                        __builtin_amdgcn_s_sleep(1);
                    }
                }
                __syncthreads();
            }

            f32x4 acc[2][4];
            #pragma unroll
            for (int p = 0; p < 2; ++p)
                #pragma unroll
                for (int nf = 0; nf < 4; ++nf) acc[p][nf] = (f32x4){0.f, 0.f, 0.f, 0.f};
            const float* xrow[2];
            #pragma unroll
            for (int p = 0; p < 2; ++p) {
                const int m = (w * 2 + p) * 16 + (l & 15);
                xrow[p] = x + ((size_t)(m & 31) * T_ + (8 * c + (m >> 5))) * 1024;
            }
            #pragma unroll 4
            for (int kiG = 0; kiG < 32; ++kiG) {
                const int kk = kiG * 32 + koff;
                f16x8 af[2];
                #pragma unroll
                for (int p = 0; p < 2; ++p) {
                    float4 v0 = *(const float4*)&xrow[p][kk];
                    float4 v1 = *(const float4*)&xrow[p][kk + 4];
                    af[p][0]=(_Float16)v0.x; af[p][1]=(_Float16)v0.y;
                    af[p][2]=(_Float16)v0.z; af[p][3]=(_Float16)v0.w;
                    af[p][4]=(_Float16)v1.x; af[p][5]=(_Float16)v1.y;
                    af[p][6]=(_Float16)v1.z; af[p][7]=(_Float16)v1.w;
                }
                #pragma unroll
                for (int nf = 0; nf < 4; ++nf) {
                    f16x8 bf = *(const f16x8*)&Wl[((nf * 32 + kiG) * 64 + l) * 8];
                    acc[0][nf] = __builtin_amdgcn_mfma_f32_16x16x32_f16(af[0], bf, acc[0][nf], 0, 0, 0);
                    acc[1][nf] = __builtin_amdgcn_mfma_f32_16x16x32_f16(af[1], bf, acc[1][nf], 0, 0, 0);
                }
            }
            #pragma unroll
            for (int p = 0; p < 2; ++p)
                #pragma unroll
                for (int nf = 0; nf < 4; ++nf)
                    #pragma unroll
                    for (int i = 0; i < 4; ++i) {
                        _Float16 hf = (_Float16)(acc[p][nf][i] + bb0[nf]);   // bias folded
                        unsigned short us; __builtin_memcpy(&us, &hf, 2);
                        unsigned up = us;
                        unsigned op = (unsigned)__shfl_xor((int)up, 1);
                        if (!(l & 1)) {
                            const int m = (w * 2 + p) * 16 + (l >> 4) * 4 + i;
                            size_t off = (((size_t)(c & 3) * 8 + (m >> 5)) * B_ + (m & 31)) * G4_
                                       + gbase + nf * 16 + ((l & 15) & ~1);
                            stA32((unsigned*)&xzr[off], up | (op << 16));
                        }
                    }
            asm volatile("s_waitcnt vmcnt(0)" ::: "memory");
            __syncthreads();
            if (tid == 0) stA32(&ctr[384 + e], (unsigned)(c + 1));
        }
        return;
    }

    // ============================ RECURRENCE DOMAINS (64+64 blocks x 16 cols) ============================
    const int dom = (bid >= 64);
    const int db  = bid & 63;
    const int jb  = db * 16;

    _Float16* stA = (_Float16*)smem;                 // 66048 B [32][ROWP]
    _Float16* stB = (_Float16*)(smem + 66048);       // 66048 B (dom1 only)
    float*    red = (float*)(smem + (dom ? 132096 : 66048));
    #define RED(slot, row, col) red[((slot) * 16 + (row)) * 17 + (col)]

    // ---- weights -> registers (AGPR-backed), bounced through LDS ----
    f16x8 wf[32];
    const int gq = w & 3;                 // gate id for this wave
    const int myrow = gq * 16 + (l & 15);
    if (dom == 0) {
        load_wfrags(U0, jb, myrow, koff, true, wf, stA);
    } else {
        const int rl = w >> 2;
        load_wfrags(W1, jb, myrow, koff, (rl == 0), wf, stA);
        load_wfrags(U1, jb, myrow, koff, (rl == 1), wf, stA);
    }

    // combine mapping (waves 0..1): 128 threads x 4 cols
    const int cidx = w * 64 + l;
    const int cb = cidx >> 2, j4 = (cidx & 3) * 4;
    float creg[4] = {0.f, 0.f, 0.f, 0.f};
    float bias_[4][4];
    if (dom == 1 && w < 2) {
        #pragma unroll
        for (int g = 0; g < 4; ++g)
            #pragma unroll
            for (int c = 0; c < 4; ++c)
                bias_[g][c] = b1[(size_t)g * H_ + jb + j4 + c];
    }
    const int mt = w >> 2;                // dom0 m-tile
    const int rl = w >> 2;                // dom1 role

    for (int t = 0; t < T_; ++t) {
        // ---- wave0 polls producer flags (lane-parallel) ----
        if (w == 0) {
            if (dom == 0) {
                const unsigned xt = (unsigned)((t >> 3) + 1);
                while (true) {
                    bool ok = (ldA(&ctr[384 + l]) >= xt);
                    if (t > 0) {
                        unsigned v0 = umin2(ldA(&ctr[2 * l]), ldA(&ctr[2 * l + 1]));
                        ok = ok && (v0 >= (unsigned)t);
                    }
                    if (__all((int)ok)) break;
                    __builtin_amdgcn_s_sleep(1);
                }
            } else {
                while (true) {
                    unsigned v0 = umin2(ldA(&ctr[2 * l]), ldA(&ctr[2 * l + 1]));
                    bool ok = (v0 >= (unsigned)(t + 1));
                    if (t > 0) {
                        unsigned v1 = umin2(ldA(&ctr[128 + 2 * l]), ldA(&ctr[128 + 2 * l + 1]));
                        ok = ok && (v1 >= (unsigned)t);
                    }
                    if (__all((int)ok)) break;
                    __builtin_amdgcn_s_sleep(1);
                }
            }
        }
        __syncthreads();   // S1: producers done, staging buffers free

        // ---- cooperative stage: flat fb = tid*16 + it*8192 (coalesced, conflict-free) ----
        if (dom == 0) {
            const char* src = t ? (const char*)(h1 + (size_t)(t - 1) * B_ * H_) : (const char*)zp;
            #pragma unroll
            for (int it = 0; it < 8; ++it) {
                const int fb = tid * 16 + it * 8192;
                const int row = fb >> 11, rb = fb & 2047;
                *(uint4*)&smem[row * 2064 + rb] = *(const uint4*)(src + fb);
            }
        } else {
            const char* s1 = (const char*)(h1 + (size_t)t * B_ * H_);
            const char* s2 = t ? (const char*)(h2 + (size_t)(t - 1) * B_ * H_) : (const char*)zp;
            #pragma unroll
            for (int it = 0; it < 8; ++it) {
                const int fb = tid * 16 + it * 8192;
                const int row = fb >> 11, rb = fb & 2047;
                *(uint4*)&smem[row * 2064 + rb] = *(const uint4*)(s1 + fb);
                *(uint4*)&smem[66048 + row * 2064 + rb] = *(const uint4*)(s2 + fb);
            }
        }
        // dom0 combine waves: issue xz bypass loads (overlap with staging drain + MFMA)
        unsigned long long xzq[4];
        if (dom == 0 && w < 2) {
            const size_t xbase = (((size_t)((t >> 3) & 3) * 8 + (t & 7)) * B_ + cb) * G4_ + jb + j4;
            #pragma unroll
            for (int gg = 0; gg < 4; ++gg) xzq[gg] = ldA64(&xzr[xbase + gg * 1024]);
        }
        __syncthreads();   // S2: stage visible

        // ---- MFMA from LDS stage x reg-weights ----
        if (dom == 0) {
            const _Float16* ar = stA + (mt * 16 + (l & 15)) * ROWP;
            f32x4 ac0 = {0,0,0,0}, ac1 = {0,0,0,0}, ac2 = {0,0,0,0}, ac3 = {0,0,0,0};
            #pragma unroll
            for (int k = 0; k < 32; k += 4) {
                ac0 = __builtin_amdgcn_mfma_f32_16x16x32_f16(*(const f16x8*)&ar[(k+0)*32 + koff], wf[k+0], ac0, 0, 0, 0);
                ac1 = __builtin_amdgcn_mfma_f32_16x16x32_f16(*(const f16x8*)&ar[(k+1)*32 + koff], wf[k+1], ac1, 0, 0, 0);
                ac2 = __builtin_amdgcn_mfma_f32_16x16x32_f16(*(const f16x8*)&ar[(k+2)*32 + koff], wf[k+2], ac2, 0, 0, 0);
                ac3 = __builtin_amdgcn_mfma_f32_16x16x32_f16(*(const f16x8*)&ar[(k+3)*32 + koff], wf[k+3], ac3, 0, 0, 0);
            }
            f32x4 acc = (ac0 + ac1) + (ac2 + ac3);
            #pragma unroll
            for (int i = 0; i < 4; ++i)
                RED(mt * 4 + gq, (l >> 4) * 4 + i, (l & 15)) = acc[i];
        } else {
            const _Float16* ab = (rl ? stB : stA);
            const _Float16* ar0 = ab + (l & 15) * ROWP;
            const _Float16* ar1 = ab + (16 + (l & 15)) * ROWP;
            f32x4 ac0 = {0,0,0,0}, ac1 = {0,0,0,0};
            #pragma unroll
            for (int k = 0; k < 32; ++k) {
                const int kk = k * 32 + koff;
                f16x8 bfr = wf[k];
                ac0 = __builtin_amdgcn_mfma_f32_16x16x32_f16(*(const f16x8*)&ar0[kk], bfr, ac0, 0, 0, 0);
                ac1 = __builtin_amdgcn_mfma_f32_16x16x32_f16(*(const f16x8*)&ar1[kk], bfr, ac1, 0, 0, 0);
            }
            #pragma unroll
            for (int i = 0; i < 4; ++i) {
                RED(rl * 8 + 0 * 4 + gq, (l >> 4) * 4 + i, (l & 15)) = ac0[i];
                RED(rl * 8 + 1 * 4 + gq, (l >> 4) * 4 + i, (l & 15)) = ac1[i];
            }
        }
        __syncthreads();   // S3: red ready

        // ---- combine + state + publish + ack + flag (waves 0..1) ----
        if (w < 2) {
            const int rmt = cb >> 4, row = cb & 15;
            unsigned long long pk = 0;
            float hv4[4];
            if (dom == 0) {
                asm volatile("s_waitcnt vmcnt(0)" ::: "memory");   // xz loads done
                #pragma unroll
                for (int c = 0; c < 4; ++c) {
                    float z[4];
                    #pragma unroll
                    for (int gg = 0; gg < 4; ++gg) {
                        float xv = f16bits_to_f((unsigned short)((xzq[gg] >> (16 * c)) & 0xffffu));
                        z[gg] = RED(rmt * 4 + gg, row, j4 + c) + xv;   // b0 folded in xz
                    }
                    float ig = hardsig(z[0]), fg = hardsig(z[1]);
                    float gv = fast_tanh(z[2]), og = hardsig(z[3]);
                    creg[c] = fg * creg[c] + ig * gv;
                    hv4[c] = og * fast_tanh(creg[c]);
                    _Float16 hf = (_Float16)hv4[c];
                    unsigned short us; __builtin_memcpy(&us, &hf, 2);
                    pk |= ((unsigned long long)us) << (16 * c);
                }
                stA64(&h1[((size_t)t * B_ + cb) * H_ + jb + j4], pk);
                asm volatile("s_waitcnt vmcnt(0)" ::: "memory");   // publish ACKed at LLC
                if (l == 0) stA32(&ctr[db * 2 + w], (unsigned)(t + 1));
            } else {
                #pragma unroll
                for (int c = 0; c < 4; ++c) {
                    float z[4];
                    #pragma unroll
                    for (int gg = 0; gg < 4; ++gg)
                        z[gg] = RED(0 + rmt * 4 + gg, row, j4 + c)
                              + RED(8 + rmt * 4 + gg, row, j4 + c) + bias_[gg][c];
                    float ig = hardsig(z[0]), fg = hardsig(z[1]);
                    float gv = fast_tanh(z[2]), og = hardsig(z[3]);
                    creg[c] = fg * creg[c] + ig * gv;
                    hv4[c] = og * fast_tanh(creg[c]);
                    _Float16 hf = (_Float16)hv4[c];
                    unsigned short us; __builtin_memcpy(&us, &hf, 2);
                    pk |= ((unsigned long long)us) << (16 * c);
                }
                stA64(&h2[((size_t)t * B_ + cb) * H_ + jb + j4], pk);
                if (t == T_ - 1)
                    *(float4*)&out[(size_t)cb * H_ + jb + j4] = make_float4(hv4[0], hv4[1], hv4[2], hv4[3]);
                asm volatile("s_waitcnt vmcnt(0)" ::: "memory");
                if (l == 0) stA32(&ctr[128 + db * 2 + w], (unsigned)(t + 1));
            }
        }
    }
}

extern "C" void kernel_launch(void* const* d_in, const int* in_sizes, int n_in,
                              void* d_out, int out_size, void* d_ws, size_t ws_size,
                              hipStream_t stream) {
    const float* x  = (const float*)d_in[0];
    const float* W0 = (const float*)d_in[1];
    const float* U0 = (const float*)d_in[2];
    const float* b0 = (const float*)d_in[3];
    const float* W1 = (const float*)d_in[4];
    const float* U1 = (const float*)d_in[5];
    const float* b1 = (const float*)d_in[6];
    float* out = (float*)d_out;

    char* ws = (char*)d_ws;
    const size_t off_h1 = 0;          // 32 MiB  h1 fp16 [T][B][H]
    const size_t off_h2 = 33554432;   // 32 MiB  h2 fp16 [T][B][H]
    const size_t off_xz = 67108864;   //  8 MiB  xz ring fp16 [4][8][B][4H]
    const size_t off_zp = 75497472;   // 64 KiB  fp16 zeros
    const size_t off_ct = 75563008;   //  8 KiB  flags

    _Float16* h1  = (_Float16*)(ws + off_h1);
    _Float16* h2  = (_Float16*)(ws + off_h2);
    _Float16* xzr = (_Float16*)(ws + off_xz);
    _Float16* zp  = (_Float16*)(ws + off_zp);
    unsigned* ctr = (unsigned*)(ws + off_ct);

    // reset zero page + flags every launch (graph-capture safe)
    hipMemsetAsync(ws + off_zp, 0, 65536 + 8192, stream);

    hipLaunchKernelGGL(lstm12, dim3(192), dim3(NT), 0, stream,
                       x, W0, U0, b0, W1, U1, b1,
                       h1, h2, xzr, zp, ctr, out);
}